// Round 3
// baseline (803.016 us; speedup 1.0000x reference)
//
#include <hip/hip_runtime.h>

#define NN 50000
#define NE 600000
#define DD 128
#define ETILES (NE/64)        // 9375
#define NTILES ((NN+63)/64)   // 782

typedef __attribute__((ext_vector_type(8))) short short8;
typedef __attribute__((ext_vector_type(4))) float f32x4;
typedef __attribute__((ext_vector_type(2))) float f32x2;
typedef unsigned short u16;

#define MFMA16(a,b,c) __builtin_amdgcn_mfma_f32_16x16x32_bf16((a),(b),(c),0,0,0)

// LDS layout (bytes):
//   A region  : 0      .. 32767  bf16 [64][256], XOR-swizzled; later holds h1 (first 16KB)
//   H region  : 32768  .. 49151  bf16 [64][128], XOR-swizzled; holds h0 then h2
//   F4 region : 49152  .. 50175  f32  [64][4]  (edge only: d0,d1,d2,norm)
//   JB region : 50176  .. 50431  int  [64]     (edge only: dest node j)
#define A_OFF 0
#define H_OFF 32768
#define F4_OFF 49152
#define JB_OFF 50176

__device__ __forceinline__ float bf2f(unsigned int u){
  union { unsigned int i; float f; } v; v.i = u << 16; return v.f;
}
__device__ __forceinline__ u16 f2bf(float f){
  union { float f; unsigned int i; } v; v.f = f;
  unsigned int r = v.i + 0x7fffu + ((v.i >> 16) & 1u);   // RNE
  return (u16)(r >> 16);
}
// A tile: row stride 512B = 32 16B-chunks; swizzle chunk ^= (row&7)
__device__ __forceinline__ int addrA(int row, int col){
  return (row<<9) + (((col>>3) ^ (row&7))<<4) + ((col&7)<<1);
}
// H tile: row stride 256B = 16 chunks; same swizzle
__device__ __forceinline__ int addrH(int row, int col){
  return (row<<8) + (((col>>3) ^ (row&7))<<4) + ((col&7)<<1);
}

// ---- repack fp32 weights [K][128] -> bf16 MFMA B-fragments -----------------
// out frag layout: [(kk*8 + colgroup)*64 + lane] -> 8 bf16 (16B per lane)
// B-frag mapping for mfma_f32_16x16x32_bf16: col = lane&15, k = (lane>>4)*8+i
__global__ void repack_kernel(const float* __restrict__ W, u16* __restrict__ out, int roff){
  const int l = threadIdx.x;
  const int gid = blockIdx.x;           // kk*8 + colgroup
  const int kk = gid >> 3, cg = gid & 7;
  const int kbase = kk*32 + ((l>>4)<<3) + roff;
  const int c = (cg<<4) + (l&15);
  short8 pk;
#pragma unroll
  for (int i=0;i<8;++i) pk[i] = (short)f2bf(W[(size_t)(kbase+i)*DD + c]);
  ((short8*)out)[gid*64 + l] = pk;
}

// one MLP layer's MFMA sweep: A from LDS (stride 2^SH bytes/row), KK K-steps of 32
template<int SH, int KK>
__device__ __forceinline__ void layer_mm(const unsigned char* lbase,
                                         const short8 (*wf)[2],
                                         f32x4 (&acc)[4][2],
                                         int l15, int l4){
#pragma unroll
  for (int kk=0; kk<KK; ++kk){
    short8 a[4];
#pragma unroll
    for (int m=0;m<4;++m){
      const int row = m*16 + l15;                 // A row = lane&15 (+ m-tile)
      const int col = kk*32 + l4*8;               // A k = (lane>>4)*8 + i
      const int c = (col>>3) ^ (row&7);
      a[m] = *(const short8*)(lbase + (row<<SH) + (c<<4));
    }
#pragma unroll
    for (int m=0;m<4;++m){
      acc[m][0] = MFMA16(a[m], wf[kk][0], acc[m][0]);
      acc[m][1] = MFMA16(a[m], wf[kk][1], acc[m][1]);
    }
  }
}

__device__ __forceinline__ void zero_acc(f32x4 (&acc)[4][2]){
#pragma unroll
  for (int m=0;m<4;++m)
#pragma unroll
    for (int n=0;n<2;++n){ f32x4 z = {0.f,0.f,0.f,0.f}; acc[m][n] = z; }
}

// C/D mapping (verified m89/m91): col = lane&15, row = (lane>>4)*4 + reg
__device__ __forceinline__ void store_h(unsigned char* hbase, f32x4 (&acc)[4][2],
                                        const float* b, bool relu,
                                        int w, int l15, int l4){
#pragma unroll
  for (int m=0;m<4;++m)
#pragma unroll
    for (int r=0;r<4;++r){
      const int row = m*16 + l4*4 + r;
#pragma unroll
      for (int n=0;n<2;++n){
        float v = acc[m][n][r] + b[n];
        if (relu) v = fmaxf(v, 0.f);
        *(u16*)(hbase + addrH(row, w*32 + n*16 + l15)) = f2bf(v);
      }
    }
}

// ---------------- edge kernel ----------------
__global__ __launch_bounds__(256, 2)
void edge_kernel(const float* __restrict__ x, const float* __restrict__ pos,
                 const int* __restrict__ g,
                 const short8* __restrict__ wf0, const short8* __restrict__ wf1,
                 const short8* __restrict__ wf2,
                 const float* __restrict__ ew0_raw,
                 const float* __restrict__ eb0, const float* __restrict__ eb1,
                 const float* __restrict__ eb2, const float* __restrict__ eg,
                 const float* __restrict__ ebeta,
                 float* aggr)
{
  __shared__ alignas(16) unsigned char lds[50432];
  const int tid = threadIdx.x;
  const int w = tid >> 6, lane = tid & 63;
  const int l15 = lane & 15, l4 = lane >> 4;

  // per-wave weight fragments (wave owns cols w*32 .. w*32+31, 2 n-tiles)
  short8 w0f[8][2], w1f[4][2], w2f[4][2];
#pragma unroll
  for (int kk=0;kk<8;++kk){
    w0f[kk][0] = wf0[(kk*8 + w*2    )*64 + lane];
    w0f[kk][1] = wf0[(kk*8 + w*2 + 1)*64 + lane];
  }
#pragma unroll
  for (int kk=0;kk<4;++kk){
    w1f[kk][0] = wf1[(kk*8 + w*2    )*64 + lane];
    w1f[kk][1] = wf1[(kk*8 + w*2 + 1)*64 + lane];
    w2f[kk][0] = wf2[(kk*8 + w*2    )*64 + lane];
    w2f[kk][1] = wf2[(kk*8 + w*2 + 1)*64 + lane];
  }
  float w4c[2][4];
#pragma unroll
  for (int n=0;n<2;++n)
#pragma unroll
    for (int q=0;q<4;++q) w4c[n][q] = ew0_raw[q*DD + w*32 + n*16 + l15];
  const float b0c[2] = { eb0[w*32 + l15], eb0[w*32 + 16 + l15] };
  const float b1c[2] = { eb1[w*32 + l15], eb1[w*32 + 16 + l15] };
  const float b2c[2] = { eb2[w*32 + l15], eb2[w*32 + 16 + l15] };
  const float egA = eg[2*lane],    egB = eg[2*lane+1];
  const float ebA = ebeta[2*lane], ebB = ebeta[2*lane+1];
  const int* gI = g;
  const int* gJ = g + NE;

  for (int t = blockIdx.x; t < ETILES; t += gridDim.x){
    const int e0 = t*64;
    // ---- gather: 4 threads/edge, 64 floats each -> bf16 -> swizzled LDS A
    {
      const int e = tid >> 2, sub = tid & 3;
      const int ii = gI[e0+e], jj = gJ[e0+e];
      const float* src = (sub < 2) ? (x + (size_t)ii*DD + sub*64)
                                   : (x + (size_t)jj*DD + (sub-2)*64);
      const int cb = sub*64;
      const float4* p = (const float4*)src;
#pragma unroll
      for (int q=0;q<8;++q){
        float4 a = p[2*q], b = p[2*q+1];
        short8 pk;
        pk[0]=(short)f2bf(a.x); pk[1]=(short)f2bf(a.y);
        pk[2]=(short)f2bf(a.z); pk[3]=(short)f2bf(a.w);
        pk[4]=(short)f2bf(b.x); pk[5]=(short)f2bf(b.y);
        pk[6]=(short)f2bf(b.z); pk[7]=(short)f2bf(b.w);
        *(short8*)(lds + A_OFF + addrA(e, cb + q*8)) = pk;
      }
      if (sub == 0){
        float d0 = pos[ii*3  ] - pos[jj*3  ];
        float d1 = pos[ii*3+1] - pos[jj*3+1];
        float d2 = pos[ii*3+2] - pos[jj*3+2];
        float nr = sqrtf(d0*d0 + d1*d1 + d2*d2);
        *(float4*)(lds + F4_OFF + e*16) = make_float4(d0,d1,d2,nr);
        ((int*)(lds + JB_OFF))[e] = jj;
      }
    }
    __syncthreads();

    f32x4 acc[4][2];
    // ---- L0: A[64][256] x ew0(x-part), + rank-4 [d,norm] update
    zero_acc(acc);
    layer_mm<9,8>(lds + A_OFF, w0f, acc, l15, l4);
#pragma unroll
    for (int m=0;m<4;++m)
#pragma unroll
      for (int r=0;r<4;++r){
        const int row = m*16 + l4*4 + r;
        float4 f = *(const float4*)(lds + F4_OFF + row*16);
#pragma unroll
        for (int n=0;n<2;++n)
          acc[m][n][r] += f.x*w4c[n][0] + f.y*w4c[n][1] + f.z*w4c[n][2] + f.w*w4c[n][3];
      }
    store_h(lds + H_OFF, acc, b0c, true, w, l15, l4);   // h0 -> H region
    __syncthreads();
    // ---- L1: h0 -> h1 (h1 overlays A region, A is dead)
    zero_acc(acc);
    layer_mm<8,4>(lds + H_OFF, w1f, acc, l15, l4);
    store_h(lds + A_OFF, acc, b1c, true, w, l15, l4);
    __syncthreads();
    // ---- L2: h1 -> h2 (h2 overlays H region, h0 is dead)
    zero_acc(acc);
    layer_mm<8,4>(lds + A_OFF, w2f, acc, l15, l4);
    store_h(lds + H_OFF, acc, b2c, false, w, l15, l4);
    __syncthreads();
    // ---- LayerNorm + scatter-add (wave w handles rows w*16..w*16+15)
    for (int rr=0; rr<16; ++rr){
      const int row = w*16 + rr;
      unsigned int pk = *(const unsigned int*)(lds + H_OFF + addrH(row, 2*lane));
      float v0 = bf2f(pk & 0xffffu), v1 = bf2f(pk >> 16);
      float s = v0 + v1, qq = v0*v0 + v1*v1;
#pragma unroll
      for (int off=1; off<64; off<<=1){
        s  += __shfl_xor(s,  off);
        qq += __shfl_xor(qq, off);
      }
      float mean = s * (1.f/128.f);
      float var  = qq * (1.f/128.f) - mean*mean;
      float rstd = rsqrtf(var + 1e-5f);
      float o0 = (v0 - mean)*rstd*egA + ebA;
      float o1 = (v1 - mean)*rstd*egB + ebB;
      const int jj = ((const int*)(lds + JB_OFF))[row];
      float* dst = aggr + (size_t)jj*DD + 2*lane;
      unsafeAtomicAdd(dst,     o0);   // native global_atomic_add_f32
      unsafeAtomicAdd(dst + 1, o1);
    }
    __syncthreads();
  }
}

// ---------------- node kernel ----------------
__global__ __launch_bounds__(256, 2)
void node_kernel(const float* __restrict__ x,
                 const short8* __restrict__ wf0, const short8* __restrict__ wf1,
                 const short8* __restrict__ wf2,
                 const float* __restrict__ nb0, const float* __restrict__ nb1,
                 const float* __restrict__ nb2, const float* __restrict__ ng,
                 const float* __restrict__ nbeta,
                 float* nio)   // aggr in, final output out (same buffer, row-disjoint)
{
  __shared__ alignas(16) unsigned char lds[49152];
  const int tid = threadIdx.x;
  const int w = tid >> 6, lane = tid & 63;
  const int l15 = lane & 15, l4 = lane >> 4;

  short8 w0f[8][2], w1f[4][2], w2f[4][2];
#pragma unroll
  for (int kk=0;kk<8;++kk){
    w0f[kk][0] = wf0[(kk*8 + w*2    )*64 + lane];
    w0f[kk][1] = wf0[(kk*8 + w*2 + 1)*64 + lane];
  }
#pragma unroll
  for (int kk=0;kk<4;++kk){
    w1f[kk][0] = wf1[(kk*8 + w*2    )*64 + lane];
    w1f[kk][1] = wf1[(kk*8 + w*2 + 1)*64 + lane];
    w2f[kk][0] = wf2[(kk*8 + w*2    )*64 + lane];
    w2f[kk][1] = wf2[(kk*8 + w*2 + 1)*64 + lane];
  }
  const float b0c[2] = { nb0[w*32 + l15], nb0[w*32 + 16 + l15] };
  const float b1c[2] = { nb1[w*32 + l15], nb1[w*32 + 16 + l15] };
  const float b2c[2] = { nb2[w*32 + l15], nb2[w*32 + 16 + l15] };
  const float ngA = ng[2*lane],    ngB = ng[2*lane+1];
  const float nbA = nbeta[2*lane], nbB = nbeta[2*lane+1];

  for (int t = blockIdx.x; t < NTILES; t += gridDim.x){
    const int n0 = t*64;
    {
      const int rloc = tid >> 2, sub = tid & 3;
      const int row = n0 + rloc;
      const int cb = sub*64;
      if (row < NN){
        const float* src = (sub < 2) ? (x   + (size_t)row*DD + sub*64)
                                     : (nio + (size_t)row*DD + (sub-2)*64);
        const float4* p = (const float4*)src;
#pragma unroll
        for (int q=0;q<8;++q){
          float4 a = p[2*q], b = p[2*q+1];
          short8 pk;
          pk[0]=(short)f2bf(a.x); pk[1]=(short)f2bf(a.y);
          pk[2]=(short)f2bf(a.z); pk[3]=(short)f2bf(a.w);
          pk[4]=(short)f2bf(b.x); pk[5]=(short)f2bf(b.y);
          pk[6]=(short)f2bf(b.z); pk[7]=(short)f2bf(b.w);
          *(short8*)(lds + A_OFF + addrA(rloc, cb + q*8)) = pk;
        }
      } else {
        short8 zk = {0,0,0,0,0,0,0,0};
#pragma unroll
        for (int q=0;q<8;++q)
          *(short8*)(lds + A_OFF + addrA(rloc, cb + q*8)) = zk;
      }
    }
    __syncthreads();

    f32x4 acc[4][2];
    zero_acc(acc);
    layer_mm<9,8>(lds + A_OFF, w0f, acc, l15, l4);
    store_h(lds + H_OFF, acc, b0c, true, w, l15, l4);
    __syncthreads();
    zero_acc(acc);
    layer_mm<8,4>(lds + H_OFF, w1f, acc, l15, l4);
    store_h(lds + A_OFF, acc, b1c, true, w, l15, l4);
    __syncthreads();
    zero_acc(acc);
    layer_mm<8,4>(lds + A_OFF, w2f, acc, l15, l4);
    store_h(lds + H_OFF, acc, b2c, false, w, l15, l4);
    __syncthreads();
    // LN + residual + store
    for (int rr=0; rr<16; ++rr){
      const int rloc = w*16 + rr;
      const int row = n0 + rloc;
      unsigned int pk = *(const unsigned int*)(lds + H_OFF + addrH(rloc, 2*lane));
      float v0 = bf2f(pk & 0xffffu), v1 = bf2f(pk >> 16);
      float s = v0 + v1, qq = v0*v0 + v1*v1;
#pragma unroll
      for (int off=1; off<64; off<<=1){
        s  += __shfl_xor(s,  off);
        qq += __shfl_xor(qq, off);
      }
      if (row < NN){
        float mean = s * (1.f/128.f);
        float var  = qq * (1.f/128.f) - mean*mean;
        float rstd = rsqrtf(var + 1e-5f);
        f32x2 xr = *(const f32x2*)(x + (size_t)row*DD + 2*lane);
        f32x2 o;
        o[0] = (v0 - mean)*rstd*ngA + nbA + xr[0];
        o[1] = (v1 - mean)*rstd*ngB + nbB + xr[1];
        *(f32x2*)(nio + (size_t)row*DD + 2*lane) = o;
      }
    }
    __syncthreads();
  }
}

extern "C" void kernel_launch(void* const* d_in, const int* in_sizes, int n_in,
                              void* d_out, int out_size, void* d_ws, size_t ws_size,
                              hipStream_t stream) {
  const float* x     = (const float*)d_in[0];
  const float* pos   = (const float*)d_in[1];
  const int*   g     = (const int*)  d_in[2];
  const float* ew0   = (const float*)d_in[3];
  const float* eb0   = (const float*)d_in[4];
  const float* ew1   = (const float*)d_in[5];
  const float* eb1   = (const float*)d_in[6];
  const float* ew2   = (const float*)d_in[7];
  const float* eb2   = (const float*)d_in[8];
  const float* eg    = (const float*)d_in[9];
  const float* ebeta = (const float*)d_in[10];
  const float* nw0   = (const float*)d_in[11];
  const float* nb0   = (const float*)d_in[12];
  const float* nw1   = (const float*)d_in[13];
  const float* nb1   = (const float*)d_in[14];
  const float* nw2   = (const float*)d_in[15];
  const float* nb2   = (const float*)d_in[16];
  const float* ng    = (const float*)d_in[17];
  const float* nbeta = (const float*)d_in[18];
  float* out = (float*)d_out;
  u16*   ws  = (u16*)d_ws;

  // repacked bf16 weight fragments in d_ws (element offsets, u16 units):
  // E0:0(32768) E1:32768(16384) E2:49152(16384) N0:65536(32768) N1:98304 N2:114688
  repack_kernel<<<dim3(64), dim3(64), 0, stream>>>(ew0, ws +      0, 4); // rows 4..259
  repack_kernel<<<dim3(32), dim3(64), 0, stream>>>(ew1, ws +  32768, 0);
  repack_kernel<<<dim3(32), dim3(64), 0, stream>>>(ew2, ws +  49152, 0);
  repack_kernel<<<dim3(64), dim3(64), 0, stream>>>(nw0, ws +  65536, 0);
  repack_kernel<<<dim3(32), dim3(64), 0, stream>>>(nw1, ws +  98304, 0);
  repack_kernel<<<dim3(32), dim3(64), 0, stream>>>(nw2, ws + 114688, 0);

  // aggr accumulator lives in d_out; zero it
  hipMemsetAsync(d_out, 0, (size_t)NN * DD * sizeof(float), stream);

  edge_kernel<<<dim3(2048), dim3(256), 0, stream>>>(
      x, pos, g,
      (const short8*)(ws +     0), (const short8*)(ws + 32768), (const short8*)(ws + 49152),
      ew0, eb0, eb1, eb2, eg, ebeta, out);

  node_kernel<<<dim3(NTILES), dim3(256), 0, stream>>>(
      x,
      (const short8*)(ws + 65536), (const short8*)(ws + 98304), (const short8*)(ws + 114688),
      nb0, nb1, nb2, ng, nbeta, out);
}